// Round 2
// baseline (256.860 us; speedup 1.0000x reference)
//
#include <hip/hip_runtime.h>
#include <math.h>

// Problem constants (from reference): w is [B, N] float32, L = 1.0
#define B_ROWS 16384
#define N_COLS 2048

// ---- ws layout (floats) ----
// [0, 8*4096)            : p2[rg][0..2048)=colsum partial, p2[rg][2048..4096)=colsum2 partial
//                          (8 row-groups; zeroed by memset, atomicAdd target)
// [32768, 32768+2048)    : mean
// [32768+2048, +4096)    : invstd
// [32768+4096, +4096+2048): per-block partials of |pair_mean| from rowpass
#define WS_P2       0
#define WS_MEAN     (8 * 4096)
#define WS_INVSTD   (8 * 4096 + N_COLS)
#define WS_PARTIALS (8 * 4096 + 2 * N_COLS)

// ---------------- Pass 1: column sums (Sum w, Sum w^2) ----------------
// 2048 blocks = 1024 rowchunks x 2 colgroups. Each thread owns 4 consecutive
// columns (one float4) and fully unrolls 16 rows -> 16 loads in flight.
constexpr int K1_BLOCK = 256;
constexpr int K1_COLGROUPS = N_COLS / (K1_BLOCK * 4);     // = 2
constexpr int K1_ROWCHUNKS = 1024;
constexpr int K1_ROWS_PER_CHUNK = B_ROWS / K1_ROWCHUNKS;  // = 16

__global__ __launch_bounds__(K1_BLOCK) void colstats_kernel(
    const float* __restrict__ w, float* __restrict__ ws) {
  const int cg = blockIdx.x % K1_COLGROUPS;
  const int rc = blockIdx.x / K1_COLGROUPS;
  const int col4 = cg * K1_BLOCK + threadIdx.x;  // float4 column index
  const int col = col4 * 4;
  const float4* __restrict__ w4 = reinterpret_cast<const float4*>(w);
  const int row_start = rc * K1_ROWS_PER_CHUNK;

  float sx = 0.f, sy = 0.f, sz = 0.f, sw = 0.f;
  float qx = 0.f, qy = 0.f, qz = 0.f, qw = 0.f;
#pragma unroll
  for (int r = 0; r < K1_ROWS_PER_CHUNK; ++r) {
    float4 v = w4[(size_t)(row_start + r) * (N_COLS / 4) + col4];
    sx += v.x; sy += v.y; sz += v.z; sw += v.w;
    qx = fmaf(v.x, v.x, qx);
    qy = fmaf(v.y, v.y, qy);
    qz = fmaf(v.z, v.z, qz);
    qw = fmaf(v.w, v.w, qw);
  }
  // Hierarchical accumulation: 8 row-groups -> 128-way contention per address.
  const int rg = rc >> 7;  // 1024 chunks / 8 groups = 128
  float* __restrict__ p2 = ws + WS_P2 + rg * 4096;
  atomicAdd(&p2[col + 0], sx);
  atomicAdd(&p2[col + 1], sy);
  atomicAdd(&p2[col + 2], sz);
  atomicAdd(&p2[col + 3], sw);
  atomicAdd(&p2[2048 + col + 0], qx);
  atomicAdd(&p2[2048 + col + 1], qy);
  atomicAdd(&p2[2048 + col + 2], qz);
  atomicAdd(&p2[2048 + col + 3], qw);
}

// ---------------- Pass 1.5: reduce row-groups, compute mean / invstd ----------------
__global__ __launch_bounds__(256) void stats_finalize_kernel(float* __restrict__ ws) {
  const int n = blockIdx.x * 256 + threadIdx.x;
  if (n >= N_COLS) return;
  float s = 0.f, q = 0.f;
#pragma unroll
  for (int rg = 0; rg < 8; ++rg) {
    s += ws[WS_P2 + rg * 4096 + n];
    q += ws[WS_P2 + rg * 4096 + 2048 + n];
  }
  const float inv_b = 1.0f / (float)B_ROWS;
  float mean = s * inv_b;
  float var = q * inv_b - mean * mean;
  ws[WS_MEAN + n] = mean;
  ws[WS_INVSTD + n] = 1.0f / sqrtf(var);
}

// ---------------- Pass 2: per-row s, s2 -> |pair_mean|, block partials ----------------
constexpr int K3_BLOCKS = 2048;
constexpr int ROWS_PER_BLOCK = B_ROWS / K3_BLOCKS;  // = 8 (2 rows per wave, concurrent)

__global__ __launch_bounds__(256) void rowpass_kernel(
    const float* __restrict__ w, const float* __restrict__ ws,
    float* __restrict__ partials) {
  __shared__ float4 sm_mean[N_COLS / 4];   // 8 KiB
  __shared__ float4 sm_inv[N_COLS / 4];    // 8 KiB
  __shared__ float warpsum[4];

  const float4* __restrict__ g_mean = reinterpret_cast<const float4*>(ws + WS_MEAN);
  const float4* __restrict__ g_inv = reinterpret_cast<const float4*>(ws + WS_INVSTD);
  for (int i = threadIdx.x; i < N_COLS / 4; i += 256) {
    sm_mean[i] = g_mean[i];
    sm_inv[i] = g_inv[i];
  }
  __syncthreads();

  const int wid = threadIdx.x >> 6;
  const int lane = threadIdx.x & 63;
  constexpr float inv_pairs = 1.0f / ((float)N_COLS * (float)(N_COLS - 1));

  // Two rows processed CONCURRENTLY per wave -> 16 float4 loads in flight.
  const int row_a = blockIdx.x * ROWS_PER_BLOCK + wid * 2;
  const float4* __restrict__ ra = reinterpret_cast<const float4*>(w + (size_t)row_a * N_COLS);
  const float4* __restrict__ rb = reinterpret_cast<const float4*>(w + (size_t)(row_a + 1) * N_COLS);

  float sa = 0.f, qa = 0.f, sb = 0.f, qb = 0.f;
#pragma unroll
  for (int k = 0; k < 8; ++k) {
    const int idx = lane + k * 64;
    float4 va = ra[idx];
    float4 vb = rb[idx];
    float4 m = sm_mean[idx];
    float4 iv = sm_inv[idx];
    float ax = (va.x - m.x) * iv.x, ay = (va.y - m.y) * iv.y;
    float az = (va.z - m.z) * iv.z, aw = (va.w - m.w) * iv.w;
    float bx = (vb.x - m.x) * iv.x, by = (vb.y - m.y) * iv.y;
    float bz = (vb.z - m.z) * iv.z, bw = (vb.w - m.w) * iv.w;
    sa += (ax + ay) + (az + aw);
    qa += fmaf(ax, ax, fmaf(ay, ay, fmaf(az, az, aw * aw)));
    sb += (bx + by) + (bz + bw);
    qb += fmaf(bx, bx, fmaf(by, by, fmaf(bz, bz, bw * bw)));
  }
  // 64-lane butterfly reduce
#pragma unroll
  for (int off = 32; off > 0; off >>= 1) {
    sa += __shfl_xor(sa, off);
    qa += __shfl_xor(qa, off);
    sb += __shfl_xor(sb, off);
    qb += __shfl_xor(qb, off);
  }
  float pm_a = (sa * sa - qa) * inv_pairs;
  float pm_b = (sb * sb - qb) * inv_pairs;
  float acc = fabsf(pm_a) + fabsf(pm_b);

  if (lane == 0) warpsum[wid] = acc;
  __syncthreads();
  if (threadIdx.x == 0)
    partials[blockIdx.x] = (warpsum[0] + warpsum[1]) + (warpsum[2] + warpsum[3]);
}

// ---------------- Final reduce ----------------
__global__ __launch_bounds__(256) void final_reduce_kernel(
    const float* __restrict__ partials, float* __restrict__ out) {
  __shared__ float warpsum[4];
  float acc = 0.f;
  for (int i = threadIdx.x; i < K3_BLOCKS; i += 256) acc += partials[i];
#pragma unroll
  for (int off = 32; off > 0; off >>= 1) acc += __shfl_xor(acc, off);
  const int wid = threadIdx.x >> 6;
  const int lane = threadIdx.x & 63;
  if (lane == 0) warpsum[wid] = acc;
  __syncthreads();
  if (threadIdx.x == 0) {
    float total = (warpsum[0] + warpsum[1]) + (warpsum[2] + warpsum[3]);
    out[0] = total * (1.0f / (float)B_ROWS);  // L = 1.0
  }
}

extern "C" void kernel_launch(void* const* d_in, const int* in_sizes, int n_in,
                              void* d_out, int out_size, void* d_ws, size_t ws_size,
                              hipStream_t stream) {
  const float* w = reinterpret_cast<const float*>(d_in[0]);
  float* out = reinterpret_cast<float*>(d_out);
  float* ws = reinterpret_cast<float*>(d_ws);

  // Zero the atomic accumulator region (ws is poisoned 0xAA before each launch).
  hipMemsetAsync(ws, 0, 8 * 4096 * sizeof(float), stream);

  colstats_kernel<<<K1_COLGROUPS * K1_ROWCHUNKS, K1_BLOCK, 0, stream>>>(w, ws);
  stats_finalize_kernel<<<(N_COLS + 255) / 256, 256, 0, stream>>>(ws);
  rowpass_kernel<<<K3_BLOCKS, 256, 0, stream>>>(w, ws, ws + WS_PARTIALS);
  final_reduce_kernel<<<1, 256, 0, stream>>>(ws + WS_PARTIALS, out);
}

// Round 3
// 219.099 us; speedup vs baseline: 1.1723x; 1.1723x over previous
//
#include <hip/hip_runtime.h>
#include <math.h>

// Problem constants (from reference): w is [B, N] float32, L = 1.0
#define B_ROWS 16384
#define N_COLS 2048

// ---- ws layout (floats) ----
// Partials: 512 rowchunks x 4096 floats each ([0,2048)=colsum, [2048,4096)=colsum2)
#define WS_PART     0
#define WS_GRP      (512 * 4096)                 // 8 groups x 4096
#define WS_MEAN     (WS_GRP + 8 * 4096)          // 2048
#define WS_INVSTD   (WS_MEAN + N_COLS)           // 2048
#define WS_RP       (WS_INVSTD + N_COLS)         // 2048 rowpass block partials
// total ~8.6 MB

// ---------------- Pass 1: per-rowchunk column partial sums ----------------
// 1024 blocks = 512 rowchunks x 2 colgroups. Each thread owns one float4 of
// columns, reduces 32 rows in two explicit 16-deep load batches (forces 16
// global_load_dwordx4 in flight), writes partial with plain stores (NO atomics).
constexpr int K1_ROWCHUNKS = 512;
constexpr int K1_ROWS = B_ROWS / K1_ROWCHUNKS;  // = 32

__global__ __launch_bounds__(256) void colstats_kernel(
    const float* __restrict__ w, float* __restrict__ part) {
  const int cg = blockIdx.x & 1;
  const int rc = blockIdx.x >> 1;
  const int tid = threadIdx.x;
  const int col4 = cg * 256 + tid;  // float4 column index in [0,512)
  const float4* __restrict__ w4 = reinterpret_cast<const float4*>(w) + col4;
  const size_t stride = N_COLS / 4;
  const size_t base = (size_t)rc * K1_ROWS * stride;

  float sx = 0.f, sy = 0.f, sz = 0.f, sw = 0.f;
  float qx = 0.f, qy = 0.f, qz = 0.f, qw = 0.f;
  for (int batch = 0; batch < K1_ROWS / 16; ++batch) {
    float4 v[16];
#pragma unroll
    for (int i = 0; i < 16; ++i)
      v[i] = w4[base + (size_t)(batch * 16 + i) * stride];
#pragma unroll
    for (int i = 0; i < 16; ++i) {
      sx += v[i].x; sy += v[i].y; sz += v[i].z; sw += v[i].w;
      qx = fmaf(v[i].x, v[i].x, qx);
      qy = fmaf(v[i].y, v[i].y, qy);
      qz = fmaf(v[i].z, v[i].z, qz);
      qw = fmaf(v[i].w, v[i].w, qw);
    }
  }
  // Partial layout per rc (as float4): [0,512)=sum by col4, [512,1024)=sum2.
  float4* __restrict__ p4 = reinterpret_cast<float4*>(part);
  p4[(size_t)rc * 1024 + col4] = make_float4(sx, sy, sz, sw);
  p4[(size_t)rc * 1024 + 512 + col4] = make_float4(qx, qy, qz, qw);
}

// ---------------- Reduce stage 1: 512 rowchunks -> 8 groups ----------------
__global__ __launch_bounds__(256) void reduce1_kernel(
    const float* __restrict__ part, float* __restrict__ grp) {
  const int t = blockIdx.x * 256 + threadIdx.x;  // 0..8191
  const int g = t >> 10;                          // group 0..7 (64 rc each)
  const int pos = t & 1023;                       // float4 position in [0,1024)
  const float4* __restrict__ p4 = reinterpret_cast<const float4*>(part);
  float ax = 0.f, ay = 0.f, az = 0.f, aw = 0.f;
  for (int b = 0; b < 8; ++b) {
    float4 v[8];
#pragma unroll
    for (int i = 0; i < 8; ++i)
      v[i] = p4[(size_t)(g * 64 + b * 8 + i) * 1024 + pos];
#pragma unroll
    for (int i = 0; i < 8; ++i) {
      ax += v[i].x; ay += v[i].y; az += v[i].z; aw += v[i].w;
    }
  }
  reinterpret_cast<float4*>(grp)[(size_t)g * 1024 + pos] =
      make_float4(ax, ay, az, aw);
}

// ---------------- Finalize: 8 groups -> mean / invstd ----------------
__global__ __launch_bounds__(256) void finalize_kernel(
    const float* __restrict__ grp, float* __restrict__ ws) {
  const int n = blockIdx.x * 256 + threadIdx.x;  // column in [0,2048)
  float s = 0.f, q = 0.f;
#pragma unroll
  for (int g = 0; g < 8; ++g) {
    s += grp[g * 4096 + n];
    q += grp[g * 4096 + 2048 + n];
  }
  const float inv_b = 1.0f / (float)B_ROWS;
  float mean = s * inv_b;
  float var = q * inv_b - mean * mean;
  ws[WS_MEAN + n] = mean;
  ws[WS_INVSTD + n] = 1.0f / sqrtf(var);
}

// ---------------- Pass 2: per-row s, s2 -> |pair_mean|, block partials ----------------
constexpr int K3_BLOCKS = 2048;
constexpr int ROWS_PER_BLOCK = B_ROWS / K3_BLOCKS;  // = 8 (2 rows per wave)

__global__ __launch_bounds__(256) void rowpass_kernel(
    const float* __restrict__ w, const float* __restrict__ ws,
    float* __restrict__ partials) {
  __shared__ float4 sm_mean[N_COLS / 4];  // 8 KiB
  __shared__ float4 sm_inv[N_COLS / 4];   // 8 KiB
  __shared__ float warpsum[4];

  const float4* __restrict__ g_mean = reinterpret_cast<const float4*>(ws + WS_MEAN);
  const float4* __restrict__ g_inv = reinterpret_cast<const float4*>(ws + WS_INVSTD);
  for (int i = threadIdx.x; i < N_COLS / 4; i += 256) {
    sm_mean[i] = g_mean[i];
    sm_inv[i] = g_inv[i];
  }
  __syncthreads();

  const int wid = threadIdx.x >> 6;
  const int lane = threadIdx.x & 63;
  constexpr float inv_pairs = 1.0f / ((float)N_COLS * (float)(N_COLS - 1));

  const int row_a = blockIdx.x * ROWS_PER_BLOCK + wid * 2;
  const float4* __restrict__ ra =
      reinterpret_cast<const float4*>(w + (size_t)row_a * N_COLS);
  const float4* __restrict__ rb =
      reinterpret_cast<const float4*>(w + (size_t)(row_a + 1) * N_COLS);

  // Batch all 16 loads (2 rows x 8) before any consumer.
  float4 va[8], vb[8];
#pragma unroll
  for (int k = 0; k < 8; ++k) va[k] = ra[lane + k * 64];
#pragma unroll
  for (int k = 0; k < 8; ++k) vb[k] = rb[lane + k * 64];

  float sa = 0.f, qa = 0.f, sb = 0.f, qb = 0.f;
#pragma unroll
  for (int k = 0; k < 8; ++k) {
    const int idx = lane + k * 64;
    float4 m = sm_mean[idx];
    float4 iv = sm_inv[idx];
    float ax = (va[k].x - m.x) * iv.x, ay = (va[k].y - m.y) * iv.y;
    float az = (va[k].z - m.z) * iv.z, aw = (va[k].w - m.w) * iv.w;
    float bx = (vb[k].x - m.x) * iv.x, by = (vb[k].y - m.y) * iv.y;
    float bz = (vb[k].z - m.z) * iv.z, bw = (vb[k].w - m.w) * iv.w;
    sa += (ax + ay) + (az + aw);
    qa += fmaf(ax, ax, fmaf(ay, ay, fmaf(az, az, aw * aw)));
    sb += (bx + by) + (bz + bw);
    qb += fmaf(bx, bx, fmaf(by, by, fmaf(bz, bz, bw * bw)));
  }
#pragma unroll
  for (int off = 32; off > 0; off >>= 1) {
    sa += __shfl_xor(sa, off);
    qa += __shfl_xor(qa, off);
    sb += __shfl_xor(sb, off);
    qb += __shfl_xor(qb, off);
  }
  float pm_a = (sa * sa - qa) * inv_pairs;
  float pm_b = (sb * sb - qb) * inv_pairs;
  float acc = fabsf(pm_a) + fabsf(pm_b);

  if (lane == 0) warpsum[wid] = acc;
  __syncthreads();
  if (threadIdx.x == 0)
    partials[blockIdx.x] = (warpsum[0] + warpsum[1]) + (warpsum[2] + warpsum[3]);
}

// ---------------- Final reduce ----------------
__global__ __launch_bounds__(256) void final_reduce_kernel(
    const float* __restrict__ partials, float* __restrict__ out) {
  __shared__ float warpsum[4];
  float acc = 0.f;
  for (int i = threadIdx.x; i < K3_BLOCKS; i += 256) acc += partials[i];
#pragma unroll
  for (int off = 32; off > 0; off >>= 1) acc += __shfl_xor(acc, off);
  const int wid = threadIdx.x >> 6;
  const int lane = threadIdx.x & 63;
  if (lane == 0) warpsum[wid] = acc;
  __syncthreads();
  if (threadIdx.x == 0) {
    float total = (warpsum[0] + warpsum[1]) + (warpsum[2] + warpsum[3]);
    out[0] = total * (1.0f / (float)B_ROWS);  // L = 1.0
  }
}

extern "C" void kernel_launch(void* const* d_in, const int* in_sizes, int n_in,
                              void* d_out, int out_size, void* d_ws, size_t ws_size,
                              hipStream_t stream) {
  const float* w = reinterpret_cast<const float*>(d_in[0]);
  float* out = reinterpret_cast<float*>(d_out);
  float* ws = reinterpret_cast<float*>(d_ws);

  colstats_kernel<<<K1_ROWCHUNKS * 2, 256, 0, stream>>>(w, ws + WS_PART);
  reduce1_kernel<<<32, 256, 0, stream>>>(ws + WS_PART, ws + WS_GRP);
  finalize_kernel<<<8, 256, 0, stream>>>(ws + WS_GRP, ws);
  rowpass_kernel<<<K3_BLOCKS, 256, 0, stream>>>(w, ws, ws + WS_RP);
  final_reduce_kernel<<<1, 256, 0, stream>>>(ws + WS_RP, out);
}